// Round 2
// baseline (837.679 us; speedup 1.0000x reference)
//
#include <hip/hip_runtime.h>
#include <stdint.h>

#define B_ 8
#define S_ 1024
#define D_ 1024
#define H_ 16
#define HD_ 64
#define KPAD 72    // K tile: 64 + 8 pad -> byte stride 144, b128 reads 2-way max
#define VPAD 136   // Vt tile: 128 + 8 pad -> byte stride 272, b128 reads 2-way max
#define PPAD 136   // P tile: 128 + 8 pad

typedef short bf16x8 __attribute__((ext_vector_type(8)));
typedef float f32x4 __attribute__((ext_vector_type(4)));

__device__ __forceinline__ unsigned short f2bf(float f) {
    union { float f; unsigned int u; } v; v.f = f;
    unsigned int r = v.u + 0x7FFFu + ((v.u >> 16) & 1u);  // RNE
    return (unsigned short)(r >> 16);
}

// 4x4 in-register transpose among 4 consecutive lanes (lane bits 0,1).
// In: lane c holds v[r] = P[r][c].  Out: lane c holds v[j] = P[c][j].
__device__ __forceinline__ void xpose4(float v[4]) {
    const int ln = threadIdx.x & 3;
    float x0 = (ln & 1) ? v[0] : v[1];
    float x1 = (ln & 1) ? v[2] : v[3];
    x0 = __shfl_xor(x0, 1);
    x1 = __shfl_xor(x1, 1);
    if (ln & 1) { v[0] = x0; v[2] = x1; } else { v[1] = x0; v[3] = x1; }
    float y0 = (ln & 2) ? v[0] : v[2];
    float y1 = (ln & 2) ? v[1] : v[3];
    y0 = __shfl_xor(y0, 2);
    y1 = __shfl_xor(y1, 2);
    if (ln & 2) { v[0] = y0; v[1] = y1; } else { v[2] = y0; v[3] = y1; }
}

// ---------------- cast x: f32 -> bf16 ----------------
__global__ __launch_bounds__(256) void cast_x_kernel(const float* __restrict__ x,
                                                     unsigned short* __restrict__ xb, int n4) {
    int i = blockIdx.x * 256 + threadIdx.x;
    if (i >= n4) return;
    float4 v = ((const float4*)x)[i];
    ushort4 o;
    o.x = f2bf(v.x); o.y = f2bf(v.y); o.z = f2bf(v.z); o.w = f2bf(v.w);
    ((ushort4*)xb)[i] = o;
}

// ---------------- transpose+cast W: Wt[z][n][k] = W_z[k][n] ----------------
__global__ __launch_bounds__(256) void transpose_w_kernel(const float* __restrict__ Wq,
                                                          const float* __restrict__ Wk,
                                                          const float* __restrict__ Wv,
                                                          unsigned short* __restrict__ Wt) {
    __shared__ float t[32][33];
    const int z = blockIdx.z;
    const float* W = (z == 0) ? Wq : (z == 1 ? Wk : Wv);
    int bx = blockIdx.x * 32, by = blockIdx.y * 32;
    int tx = threadIdx.x, ty = threadIdx.y;  // 32 x 8
    for (int i = 0; i < 4; i++)
        t[ty + 8 * i][tx] = W[(size_t)(by + ty + 8 * i) * D_ + bx + tx];
    __syncthreads();
    unsigned short* o = Wt + (size_t)z * D_ * D_;
    for (int i = 0; i < 4; i++)
        o[(size_t)(bx + ty + 8 * i) * D_ + by + tx] = f2bf(t[tx][ty + 8 * i]);
}

// ---------------- fused QKV projection (reg-staged LDS, round-0-proven staging) --------
// grid: x = 64 m-tiles, y = 24 (which*8 + n-tile). 128x128 tile, BK=64, 4 waves 2x2.
// which==2 (V) writes V TRANSPOSED: Vt[b][h][d][s] so attention needs no LDS transpose.
__global__ __launch_bounds__(256) void qkv_gemm_kernel(const unsigned short* __restrict__ Xb,
                                                       const unsigned short* __restrict__ Wt,
                                                       const float* __restrict__ bq,
                                                       const float* __restrict__ bk,
                                                       const float* __restrict__ bv,
                                                       unsigned short* __restrict__ Yb) {
    __shared__ unsigned short Xs[128 * KPAD];
    __shared__ unsigned short Ws[128 * KPAD];

    const int which = blockIdx.y >> 3;
    const int n0 = (blockIdx.y & 7) * 128;
    const int m0 = blockIdx.x * 128;
    const int tid = threadIdx.x;
    const int wave = tid >> 6, lane = tid & 63, quad = lane >> 4, l15 = lane & 15;
    const int wm = wave >> 1, wn = wave & 1;

    const float* bias = (which == 0) ? bq : (which == 1 ? bk : bv);
    const float scale = (which == 0) ? 0.03125f : 1.0f;  // fold 1/sqrt(D)=1/32 into Q
    const unsigned short* Wm = Wt + (size_t)which * D_ * D_;

    f32x4 zero = {0.f, 0.f, 0.f, 0.f};
    f32x4 acc[4][4];
    for (int mt = 0; mt < 4; mt++)
        for (int nt = 0; nt < 4; nt++) acc[mt][nt] = zero;

    for (int kt = 0; kt < 16; kt++) {
        const int k0 = kt * 64;
        __syncthreads();
        for (int i = 0; i < 4; i++) {
            int c = tid + 256 * i;
            int row = c >> 3, cc = (c & 7) * 8;
            *(int4*)&Xs[row * KPAD + cc] = *(const int4*)&Xb[(size_t)(m0 + row) * D_ + k0 + cc];
            *(int4*)&Ws[row * KPAD + cc] = *(const int4*)&Wm[(size_t)(n0 + row) * D_ + k0 + cc];
        }
        __syncthreads();
        bf16x8 af[4][2];
        for (int mt = 0; mt < 4; mt++)
            for (int ks = 0; ks < 2; ks++)
                af[mt][ks] = *(const bf16x8*)&Xs[(wm * 64 + mt * 16 + l15) * KPAD + ks * 32 + quad * 8];
        for (int nt = 0; nt < 4; nt++) {
            bf16x8 b0 = *(const bf16x8*)&Ws[(wn * 64 + nt * 16 + l15) * KPAD + quad * 8];
            bf16x8 b1 = *(const bf16x8*)&Ws[(wn * 64 + nt * 16 + l15) * KPAD + 32 + quad * 8];
            for (int mt = 0; mt < 4; mt++) {
                acc[mt][nt] = __builtin_amdgcn_mfma_f32_16x16x32_bf16(af[mt][0], b0, acc[mt][nt], 0, 0, 0);
                acc[mt][nt] = __builtin_amdgcn_mfma_f32_16x16x32_bf16(af[mt][1], b1, acc[mt][nt], 0, 0, 0);
            }
        }
    }

    if (which < 2) {
        unsigned short* Y = Yb + (size_t)which * (size_t)(B_ * S_) * D_;
        for (int mt = 0; mt < 4; mt++) {
            int rbase = m0 + wm * 64 + mt * 16 + quad * 4;
            for (int nt = 0; nt < 4; nt++) {
                int colL = n0 + wn * 64 + nt * 16 + l15;
                float bcol = bias[colL];
                float p[4];
                for (int r = 0; r < 4; r++) p[r] = (acc[mt][nt][r] + bcol) * scale;
                xpose4(p);  // lane now holds one row, 4 consecutive cols
                int row = rbase + (l15 & 3);
                int col = n0 + wn * 64 + nt * 16 + (l15 >> 2) * 4;
                ushort4 o;
                o.x = f2bf(p[0]); o.y = f2bf(p[1]); o.z = f2bf(p[2]); o.w = f2bf(p[3]);
                *(ushort4*)&Y[(size_t)row * D_ + col] = o;
            }
        }
    } else {
        // V^T epilogue: acc rows (m = b*S + s, 4 consecutive s) are already the fast axis
        unsigned short* Vt = Yb + (size_t)2 * (size_t)(B_ * S_) * D_;
        for (int mt = 0; mt < 4; mt++) {
            int m = m0 + wm * 64 + mt * 16 + quad * 4;
            int bb = m >> 10, s = m & 1023;
            for (int nt = 0; nt < 4; nt++) {
                int col = n0 + wn * 64 + nt * 16 + l15;  // feature idx: h = col>>6, d = col&63
                float bcol = bias[col];
                ushort4 o;
                o.x = f2bf(acc[mt][nt][0] + bcol);
                o.y = f2bf(acc[mt][nt][1] + bcol);
                o.z = f2bf(acc[mt][nt][2] + bcol);
                o.w = f2bf(acc[mt][nt][3] + bcol);
                *(ushort4*)&Vt[((size_t)(bb * 16 + (col >> 6)) * 64 + (col & 63)) * S_ + s] = o;
            }
        }
    }
}

// ---------------- attention: two-pass softmax, writes attn_prob + out ----------------
// grid: x = 8 q-tiles, y = 128 (b*16 + h). block 256 (4 waves, 32 q-rows each).
// V comes in pre-transposed [B][H][HD][S] -> coalesced staging, no LDS transpose.
__global__ __launch_bounds__(256) void attn_kernel(const unsigned short* __restrict__ Qb,
                                                   const unsigned short* __restrict__ Kb,
                                                   const unsigned short* __restrict__ Vtg,
                                                   float* __restrict__ out,
                                                   float* __restrict__ attnp) {
    __shared__ unsigned short Ks[128 * KPAD];   // K-tile [s_local][hd]
    __shared__ unsigned short Vts[64 * VPAD];   // V^T-tile [hd][s_local]
    __shared__ unsigned short Ps[128 * PPAD];   // P-tile bf16 [q_local][s_local]

    const int bh = blockIdx.y;
    const int b = bh >> 4, h = bh & 15;
    const int q0 = blockIdx.x * 128;
    const int tid = threadIdx.x;
    const int wave = tid >> 6, lane = tid & 63, quad = lane >> 4, l15 = lane & 15;

    const unsigned short* Vg = Vtg + (size_t)(b * 16 + h) * 64 * S_;

    // Q fragments in registers for the whole block (A-operand layout)
    bf16x8 qf[2][2];
    for (int mt = 0; mt < 2; mt++)
        for (int ks = 0; ks < 2; ks++)
            qf[mt][ks] = *(const bf16x8*)&Qb[(size_t)(b * S_ + q0 + wave * 32 + mt * 16 + l15) * D_ +
                                            h * HD_ + ks * 32 + quad * 8];

    float mrun[2][4], lrun[2][4];
    for (int mt = 0; mt < 2; mt++)
        for (int r = 0; r < 4; r++) { mrun[mt][r] = -1e30f; lrun[mt][r] = 0.f; }

    f32x4 zero = {0.f, 0.f, 0.f, 0.f};

    // ---- pass 1: row max + sum(exp) (online) ----
    for (int kt = 0; kt < 8; kt++) {
        __syncthreads();
        for (int i = 0; i < 4; i++) {
            int c = tid + 256 * i;
            int row = c >> 3, cc = (c & 7) * 8;
            *(int4*)&Ks[row * KPAD + cc] = *(const int4*)&Kb[(size_t)(b * S_ + kt * 128 + row) * D_ + h * HD_ + cc];
        }
        __syncthreads();
        f32x4 acc[2][8];
        for (int mt = 0; mt < 2; mt++)
            for (int nt = 0; nt < 8; nt++) acc[mt][nt] = zero;
        for (int nt = 0; nt < 8; nt++) {
            bf16x8 b0 = *(const bf16x8*)&Ks[(nt * 16 + l15) * KPAD + quad * 8];
            bf16x8 b1 = *(const bf16x8*)&Ks[(nt * 16 + l15) * KPAD + 32 + quad * 8];
            for (int mt = 0; mt < 2; mt++) {
                acc[mt][nt] = __builtin_amdgcn_mfma_f32_16x16x32_bf16(qf[mt][0], b0, acc[mt][nt], 0, 0, 0);
                acc[mt][nt] = __builtin_amdgcn_mfma_f32_16x16x32_bf16(qf[mt][1], b1, acc[mt][nt], 0, 0, 0);
            }
        }
        for (int mt = 0; mt < 2; mt++) {
            for (int r = 0; r < 4; r++) {
                float tm = acc[mt][0][r];
                for (int nt = 1; nt < 8; nt++) tm = fmaxf(tm, acc[mt][nt][r]);
                for (int d = 1; d < 16; d <<= 1) tm = fmaxf(tm, __shfl_xor(tm, d));
                float mnew = fmaxf(mrun[mt][r], tm);
                float s = 0.f;
                for (int nt = 0; nt < 8; nt++) s += __expf(acc[mt][nt][r] - mnew);
                for (int d = 1; d < 16; d <<= 1) s += __shfl_xor(s, d);
                lrun[mt][r] = lrun[mt][r] * __expf(mrun[mt][r] - mnew) + s;
                mrun[mt][r] = mnew;
            }
        }
    }

    float invl[2][4];
    for (int mt = 0; mt < 2; mt++)
        for (int r = 0; r < 4; r++) invl[mt][r] = 1.0f / lrun[mt][r];

    f32x4 oacc[2][4];
    for (int mt = 0; mt < 2; mt++)
        for (int nv = 0; nv < 4; nv++) oacc[mt][nv] = zero;

    float* attn_base = attnp + (size_t)bh * S_ * S_;

    // ---- pass 2: final P (float4 to global + b64 bf16 to LDS) and O += P@V ----
    for (int kt = 0; kt < 8; kt++) {
        __syncthreads();
        for (int i = 0; i < 4; i++) {
            int c = tid + 256 * i;
            int krow = c >> 3, kcc = (c & 7) * 8;
            *(int4*)&Ks[krow * KPAD + kcc] = *(const int4*)&Kb[(size_t)(b * S_ + kt * 128 + krow) * D_ + h * HD_ + kcc];
            int vrow = c >> 4, vcc = (c & 15) * 8;
            *(int4*)&Vts[vrow * VPAD + vcc] = *(const int4*)&Vg[(size_t)vrow * S_ + kt * 128 + vcc];
        }
        __syncthreads();
        f32x4 acc[2][8];
        for (int mt = 0; mt < 2; mt++)
            for (int nt = 0; nt < 8; nt++) acc[mt][nt] = zero;
        for (int nt = 0; nt < 8; nt++) {
            bf16x8 b0 = *(const bf16x8*)&Ks[(nt * 16 + l15) * KPAD + quad * 8];
            bf16x8 b1 = *(const bf16x8*)&Ks[(nt * 16 + l15) * KPAD + 32 + quad * 8];
            for (int mt = 0; mt < 2; mt++) {
                acc[mt][nt] = __builtin_amdgcn_mfma_f32_16x16x32_bf16(qf[mt][0], b0, acc[mt][nt], 0, 0, 0);
                acc[mt][nt] = __builtin_amdgcn_mfma_f32_16x16x32_bf16(qf[mt][1], b1, acc[mt][nt], 0, 0, 0);
            }
        }
        for (int mt = 0; mt < 2; mt++) {
            for (int nt = 0; nt < 8; nt++) {
                float p[4];
                for (int r = 0; r < 4; r++)
                    p[r] = __expf(acc[mt][nt][r] - mrun[mt][r]) * invl[mt][r];
                xpose4(p);  // lane: one q-row, 4 consecutive k-cols
                int rl = wave * 32 + mt * 16 + quad * 4 + (l15 & 3);
                int cl = nt * 16 + (l15 >> 2) * 4;
                float4 f4; f4.x = p[0]; f4.y = p[1]; f4.z = p[2]; f4.w = p[3];
                *(float4*)&attn_base[(size_t)(q0 + rl) * S_ + kt * 128 + cl] = f4;
                unsigned int lo = ((unsigned int)f2bf(p[1]) << 16) | f2bf(p[0]);
                unsigned int hi = ((unsigned int)f2bf(p[3]) << 16) | f2bf(p[2]);
                *(uint2*)&Ps[rl * PPAD + cl] = make_uint2(lo, hi);
            }
        }
        __syncthreads();  // Ps/Vts visible before fragment reads
        for (int kc = 0; kc < 4; kc++) {
            bf16x8 af[2];
            for (int mt = 0; mt < 2; mt++)
                af[mt] = *(const bf16x8*)&Ps[(wave * 32 + mt * 16 + l15) * PPAD + kc * 32 + quad * 8];
            for (int nv = 0; nv < 4; nv++) {
                bf16x8 bfv = *(const bf16x8*)&Vts[(nv * 16 + l15) * VPAD + kc * 32 + quad * 8];
                for (int mt = 0; mt < 2; mt++)
                    oacc[mt][nv] = __builtin_amdgcn_mfma_f32_16x16x32_bf16(af[mt], bfv, oacc[mt][nv], 0, 0, 0);
            }
        }
    }

    for (int mt = 0; mt < 2; mt++) {
        for (int nv = 0; nv < 4; nv++) {
            float o[4];
            for (int r = 0; r < 4; r++) o[r] = oacc[mt][nv][r];
            xpose4(o);
            int row = q0 + wave * 32 + mt * 16 + quad * 4 + (l15 & 3);
            int col = h * HD_ + nv * 16 + (l15 >> 2) * 4;
            float4 f4; f4.x = o[0]; f4.y = o[1]; f4.z = o[2]; f4.w = o[3];
            *(float4*)&out[(size_t)(b * S_ + row) * D_ + col] = f4;
        }
    }
}

extern "C" void kernel_launch(void* const* d_in, const int* in_sizes, int n_in,
                              void* d_out, int out_size, void* d_ws, size_t ws_size,
                              hipStream_t stream) {
    const float* x  = (const float*)d_in[0];
    const float* Wq = (const float*)d_in[1];
    const float* bq = (const float*)d_in[2];
    const float* Wk = (const float*)d_in[3];
    const float* bk = (const float*)d_in[4];
    const float* Wv = (const float*)d_in[5];
    const float* bv = (const float*)d_in[6];
    float* out = (float*)d_out;
    float* attnp = out + (size_t)B_ * S_ * D_;

    // workspace: Xb (16.8MB) | Wt x3 (6.3MB) | Q/K/V^T bf16 (50.3MB) = 73.4MB
    unsigned short* Xb = (unsigned short*)d_ws;
    unsigned short* Wt = Xb + (size_t)B_ * S_ * D_;
    unsigned short* Yb = Wt + (size_t)3 * D_ * D_;
    unsigned short* Qb = Yb;
    unsigned short* Kb = Yb + (size_t)B_ * S_ * D_;
    unsigned short* Vtg = Kb + (size_t)B_ * S_ * D_;   // [B][H][HD][S]

    int n4 = B_ * S_ * D_ / 4;
    cast_x_kernel<<<(n4 + 255) / 256, 256, 0, stream>>>(x, Xb, n4);
    transpose_w_kernel<<<dim3(32, 32, 3), dim3(32, 8), 0, stream>>>(Wq, Wk, Wv, Wt);
    qkv_gemm_kernel<<<dim3(64, 24), 256, 0, stream>>>(Xb, Wt, bq, bk, bv, Yb);
    attn_kernel<<<dim3(8, 128), 256, 0, stream>>>(Qb, Kb, Vtg, out, attnp);
}